// Round 1
// baseline (727.643 us; speedup 1.0000x reference)
//
#include <hip/hip_runtime.h>
#include <hip/hip_bf16.h>
#include <stdint.h>

typedef __attribute__((ext_vector_type(8))) short bf16x8;
typedef __attribute__((ext_vector_type(4))) float f32x4;

#define MT 128                       // edges per block
#define XP 264                       // X LDS pitch (bf16 elems): 528B rows -> 2-way bank alias only
#define PK 40                        // packed weight k-pitch (bf16 elems): 80B rows, 16B aligned
#define CHUNK_ELEMS (256 * PK)       // 10240 bf16
#define CHUNK_BYTES (CHUNK_ELEMS * 2) // 20480 B = 4 waves * 5 iters * 64 lanes * 16B

// generic->AS cast through integer (LDS aperture is 4GB aligned: low32 = as3 offset)
#define AS3U32(p) ((__attribute__((address_space(3))) uint32_t*)(uintptr_t)(p))
#define AS1U32(p) ((const __attribute__((address_space(1))) uint32_t*)(uintptr_t)(p))

// ---- pre-kernel: pack fp32 row-major W[K][256] -> bf16 chunk-transposed [c][n][kk] ----
__global__ void pack_weights(const float* __restrict__ Win,
                             const float* __restrict__ W1,
                             const float* __restrict__ W2,
                             __hip_bfloat16* __restrict__ wp)
{
    int idx = blockIdx.x * blockDim.x + threadIdx.x;   // (l,c,n)
    if (idx >= 3 * 8 * 256) return;
    int n = idx & 255;
    int c = (idx >> 8) & 7;
    int l = idx >> 11;
    const float* W = (l == 0) ? Win : (l == 1) ? W1 : W2;
    const float* src = W + (size_t)(c * 32) * 256 + n;           // rows c*32..+31, col n
    __hip_bfloat16* dst = wp + (size_t)(l * 8 + c) * CHUNK_ELEMS + n * PK;
    #pragma unroll
    for (int kk = 0; kk < 32; ++kk)
        dst[kk] = __float2bfloat16(src[(size_t)kk * 256]);
}

// ---- async stage one 20480B chunk global->LDS (all 256 threads, no divergence) ----
__device__ __forceinline__ void stage_chunk(const __hip_bfloat16* __restrict__ src,
                                            __hip_bfloat16* dst, int wave, int lane)
{
    #pragma unroll
    for (int i = 0; i < 5; ++i) {
        int unit = wave * 5 + i;                        // wave-uniform
        __builtin_amdgcn_global_load_lds(
            AS1U32((const char*)src + unit * 1024 + lane * 16),
            AS3U32((char*)dst + unit * 1024),           // HW adds lane*16
            16, 0, 0);
    }
}

__global__ __launch_bounds__(256, 1) void interp_fused(
    const float* __restrict__ pos_src, const float* __restrict__ pos_tgt,
    const float* __restrict__ latents,
    const int* __restrict__ rowi, const int* __restrict__ coli,
    const float* __restrict__ Win, const float* __restrict__ b_in,
    const float* __restrict__ b1, const float* __restrict__ b2,
    const float* __restrict__ Wout, const float* __restrict__ b_out,
    const __hip_bfloat16* __restrict__ wpack,
    float* __restrict__ out, int E)
{
    __shared__ __align__(16) __hip_bfloat16 Xs[MT * XP];          // 67584 B
    __shared__ __align__(16) __hip_bfloat16 Ws[2][CHUNK_ELEMS];   // 40960 B
    __shared__ float posrel[MT][4];                               // 2048 B
    __shared__ float biasL[3][256];                               // 3072 B
    __shared__ float w0[256];                                     // 1024 B
    __shared__ float wpos[3][256];                                // 3072 B
    __shared__ float red[4][MT];                                  // 2048 B

    const int tid  = threadIdx.x;
    const int wave = tid >> 6;
    const int lane = tid & 63;
    const int q    = lane >> 4;      // quad 0..3
    const int lm   = lane & 15;
    const int nb   = wave * 64;      // this wave's N-block
    const int base = blockIdx.x * MT;

    // issue layer0 chunk0 staging ASAP (async, overlaps gather below)
    stage_chunk(wpack, Ws[0], wave, lane);

    // stage small fp32 tables
    {
        int t = tid;
        biasL[0][t] = b_in[t];
        biasL[1][t] = b1[t];
        biasL[2][t] = b2[t];
        w0[t]       = Wout[t * 2];          // column 0 of W_out
        wpos[0][t]  = Win[256 * 256 + t];   // rows 256..258 of W_in (pos part)
        wpos[1][t]  = Win[257 * 256 + t];
        wpos[2][t]  = Win[258 * 256 + t];
    }

    // relative positions (fp32)
    if (tid < MT) {
        int e = base + tid; if (e >= E) e = E - 1;
        int ri = rowi[e], ci = coli[e];
        posrel[tid][0] = pos_tgt[ri * 3 + 0] - pos_src[ci * 3 + 0];
        posrel[tid][1] = pos_tgt[ri * 3 + 1] - pos_src[ci * 3 + 1];
        posrel[tid][2] = pos_tgt[ri * 3 + 2] - pos_src[ci * 3 + 2];
    }

    // gather latents -> Xs (bf16), 2 threads per edge, 16B LDS writes
    {
        int r = tid >> 1, h = tid & 1;
        int e = base + r; if (e >= E) e = E - 1;
        int ci = coli[e];
        const float4* src = (const float4*)(latents + (size_t)ci * 256 + h * 128);
        #pragma unroll
        for (int i = 0; i < 16; ++i) {
            float4 v0 = src[2 * i], v1 = src[2 * i + 1];
            union { bf16x8 v; __hip_bfloat16 h8[8]; } u;
            u.h8[0] = __float2bfloat16(v0.x); u.h8[1] = __float2bfloat16(v0.y);
            u.h8[2] = __float2bfloat16(v0.z); u.h8[3] = __float2bfloat16(v0.w);
            u.h8[4] = __float2bfloat16(v1.x); u.h8[5] = __float2bfloat16(v1.y);
            u.h8[6] = __float2bfloat16(v1.z); u.h8[7] = __float2bfloat16(v1.w);
            *(bf16x8*)&Xs[r * XP + h * 128 + i * 8] = u.v;
        }
    }
    __syncthreads();   // drains chunk0 staging (vmcnt) + gather ds_writes

    f32x4 acc[8][4];
    #pragma unroll
    for (int mt = 0; mt < 8; ++mt)
        #pragma unroll
        for (int nt = 0; nt < 4; ++nt)
            acc[mt][nt] = (f32x4){0.f, 0.f, 0.f, 0.f};

    for (int l = 0; l < 3; ++l) {
        for (int c = 0; c < 8; ++c) {
            const int cur = c & 1;
            // prefetch next chunk (or next layer's chunk 0) into the other buffer
            if (c < 7)
                stage_chunk(wpack + (size_t)(l * 8 + c + 1) * CHUNK_ELEMS, Ws[cur ^ 1], wave, lane);
            else if (l < 2)
                stage_chunk(wpack + (size_t)((l + 1) * 8) * CHUNK_ELEMS, Ws[cur ^ 1], wave, lane);

            bf16x8 b[4], a[8];
            #pragma unroll
            for (int nt = 0; nt < 4; ++nt)
                b[nt] = *(const bf16x8*)&Ws[cur][(nb + nt * 16 + lm) * PK + q * 8];
            #pragma unroll
            for (int mt = 0; mt < 8; ++mt)
                a[mt] = *(const bf16x8*)&Xs[(mt * 16 + lm) * XP + c * 32 + q * 8];
            #pragma unroll
            for (int mt = 0; mt < 8; ++mt)
                #pragma unroll
                for (int nt = 0; nt < 4; ++nt)
                    acc[mt][nt] = __builtin_amdgcn_mfma_f32_16x16x32_bf16(
                        a[mt], b[nt], acc[mt][nt], 0, 0, 0);
            __syncthreads();   // staging for next chunk drained; safe to swap buffers
        }

        if (l < 2) {
            // epilogue: (+pos rank-3 in fp32 for l==0) + bias, relu, write bf16 activations
            #pragma unroll
            for (int mt = 0; mt < 8; ++mt) {
                #pragma unroll
                for (int nt = 0; nt < 4; ++nt) {
                    const int n = nb + nt * 16 + lm;
                    const float bb = biasL[l][n];
                    float wp0 = 0.f, wp1 = 0.f, wp2 = 0.f;
                    if (l == 0) { wp0 = wpos[0][n]; wp1 = wpos[1][n]; wp2 = wpos[2][n]; }
                    #pragma unroll
                    for (int rg = 0; rg < 4; ++rg) {
                        const int r = mt * 16 + q * 4 + rg;   // C-layout: col=lm, row=q*4+rg
                        float v = acc[mt][nt][rg] + bb;
                        if (l == 0)
                            v += posrel[r][0] * wp0 + posrel[r][1] * wp1 + posrel[r][2] * wp2;
                        if (v < 0.f) v = 0.f;
                        Xs[r * XP + n] = __float2bfloat16(v);
                        acc[mt][nt][rg] = 0.f;
                    }
                }
            }
            __syncthreads();
        } else {
            // final: out[e] = sum_n (H3[e,n] + b2[n]) * Wout[n,0] + b_out[0], all fp32
            float partial[8][4];
            #pragma unroll
            for (int mt = 0; mt < 8; ++mt)
                #pragma unroll
                for (int rg = 0; rg < 4; ++rg) partial[mt][rg] = 0.f;
            #pragma unroll
            for (int nt = 0; nt < 4; ++nt) {
                const int n = nb + nt * 16 + lm;
                const float wn = w0[n], bn = biasL[2][n];
                #pragma unroll
                for (int mt = 0; mt < 8; ++mt)
                    #pragma unroll
                    for (int rg = 0; rg < 4; ++rg)
                        partial[mt][rg] += (acc[mt][nt][rg] + bn) * wn;
            }
            #pragma unroll
            for (int mt = 0; mt < 8; ++mt)
                #pragma unroll
                for (int rg = 0; rg < 4; ++rg) {
                    float v = partial[mt][rg];
                    v += __shfl_xor(v, 1);
                    v += __shfl_xor(v, 2);
                    v += __shfl_xor(v, 4);
                    v += __shfl_xor(v, 8);
                    partial[mt][rg] = v;
                }
            if (lm == 0) {
                #pragma unroll
                for (int mt = 0; mt < 8; ++mt)
                    #pragma unroll
                    for (int rg = 0; rg < 4; ++rg)
                        red[wave][mt * 16 + q * 4 + rg] = partial[mt][rg];
            }
            __syncthreads();
            if (tid < MT) {
                int e = base + tid;
                if (e < E)
                    out[e] = red[0][tid] + red[1][tid] + red[2][tid] + red[3][tid] + b_out[0];
            }
        }
    }
}

extern "C" void kernel_launch(void* const* d_in, const int* in_sizes, int n_in,
                              void* d_out, int out_size, void* d_ws, size_t ws_size,
                              hipStream_t stream)
{
    const float* pos_src = (const float*)d_in[0];
    const float* pos_tgt = (const float*)d_in[1];
    const float* latents = (const float*)d_in[2];
    const int*   rowi    = (const int*)d_in[3];
    const int*   coli    = (const int*)d_in[4];
    const float* Win     = (const float*)d_in[5];
    const float* b_in    = (const float*)d_in[6];
    const float* W1      = (const float*)d_in[7];
    const float* b1      = (const float*)d_in[8];
    const float* W2      = (const float*)d_in[9];
    const float* b2      = (const float*)d_in[10];
    const float* Wout    = (const float*)d_in[11];
    const float* b_out   = (const float*)d_in[12];
    float* out = (float*)d_out;
    const int E = in_sizes[3];

    __hip_bfloat16* wpack = (__hip_bfloat16*)d_ws;   // needs 3*8*20480 = 491520 B

    pack_weights<<<(3 * 8 * 256 + 255) / 256, 256, 0, stream>>>(Win, W1, W2, wpack);

    const int nblk = (E + MT - 1) / MT;
    interp_fused<<<nblk, 256, 0, stream>>>(pos_src, pos_tgt, latents, rowi, coli,
                                           Win, b_in, b1, b2, Wout, b_out,
                                           wpack, out, E);
}

// Round 2
// 416.617 us; speedup vs baseline: 1.7466x; 1.7466x over previous
//
#include <hip/hip_runtime.h>
#include <hip/hip_bf16.h>
#include <stdint.h>

typedef __attribute__((ext_vector_type(8))) short bf16x8;
typedef __attribute__((ext_vector_type(4))) float f32x4;

#define CHUNK_BYTES 16384          // one K-chunk: 32 k-rows x 256 feats bf16, swizzled
#define NSRC 100000
#define W0_OFF   (24 * CHUNK_BYTES)            // float w0[256]
#define S_OFF    (W0_OFF + 1024)               // float S = dot(b2,w0)+b_out
#define Y_OFF    (512 * 1024)                  // bf16 Y[NSRC][256]

#define AS3U32(p) ((__attribute__((address_space(3))) uint32_t*)(uintptr_t)(p))
#define AS1U32(p) ((const __attribute__((address_space(1))) uint32_t*)(uintptr_t)(p))

// swizzled chunk layout: element (k = c*32 + gk*8 + j, m) at
//   chunk + m*64 + ((gk ^ ((m>>1)&3))<<4) + j*2
// A-frag read (lane q,lm; m = wbase+mt*16+lm; k-group gk=q) is 2-way-conflict max.
// Activation row layout: edge-slot r, feat-group g (8 feats) at
//   Xs + r*512 + ((g ^ (r&31))<<4)   -> B-frag reads + b64 epilogue writes 2-way max.

// ---------------- pack: weights -> swizzled bf16 chunks; also w0 + S ----------------
__global__ __launch_bounds__(256) void pack_weights(
    const float* __restrict__ Win, const float* __restrict__ W1,
    const float* __restrict__ W2, const float* __restrict__ Wout,
    const float* __restrict__ b2, const float* __restrict__ b_out,
    char* __restrict__ wp)
{
    __shared__ float tile[32][260];
    __shared__ float rbuf[4];
    const int blk = blockIdx.x, t = threadIdx.x;
    if (blk == 24) {                       // w0 pack + scalar S
        float w = Wout[t * 2];
        ((float*)(wp + W0_OFF))[t] = w;
        float v = b2[t] * w;
        v += __shfl_xor(v, 1);  v += __shfl_xor(v, 2);  v += __shfl_xor(v, 4);
        v += __shfl_xor(v, 8);  v += __shfl_xor(v, 16); v += __shfl_xor(v, 32);
        if ((t & 63) == 0) rbuf[t >> 6] = v;
        __syncthreads();
        if (t == 0)
            *((float*)(wp + S_OFF)) = rbuf[0] + rbuf[1] + rbuf[2] + rbuf[3] + b_out[0];
        return;
    }
    const int l = blk >> 3, c = blk & 7;
    const float* W = (l == 0) ? Win : (l == 1) ? W1 : W2;
    for (int i = 0; i < 32; ++i)                    // coalesced row loads
        tile[i][t] = W[(size_t)(c * 32 + i) * 256 + t];
    __syncthreads();
    char* outrow = wp + (size_t)blk * CHUNK_BYTES + t * 64;   // t == m
    const int sw = (t >> 1) & 3;
    #pragma unroll
    for (int gk = 0; gk < 4; ++gk) {
        union { bf16x8 v; __hip_bfloat16 h[8]; } u;
        #pragma unroll
        for (int j = 0; j < 8; ++j) u.h[j] = __float2bfloat16(tile[gk * 8 + j][t]);
        *(bf16x8*)(outrow + ((gk ^ sw) << 4)) = u.v;
    }
}

__device__ __forceinline__ void stage_chunk(const char* __restrict__ src,
                                            char* dst, int wave, int lane)
{
    #pragma unroll
    for (int i = 0; i < 4; ++i) {
        int unit = wave * 4 + i;                    // wave-uniform
        __builtin_amdgcn_global_load_lds(AS1U32(src + unit * 1024 + lane * 16),
                                         AS3U32(dst + unit * 1024), 16, 0, 0);
    }
}

// ---------------- precompute: Y[s] = latents[s] @ Win[0:256] + b_in (bf16) ----------
__global__ __launch_bounds__(256, 2) void precompute_y(
    const float* __restrict__ latents, const float* __restrict__ b_in,
    const char* __restrict__ wp, char* __restrict__ Yc)
{
    __shared__ __align__(16) char Xs[64 * 512];
    __shared__ __align__(16) char Ws[2][CHUNK_BYTES];
    const int tid = threadIdx.x, wave = tid >> 6, lane = tid & 63;
    const int q = lane >> 4, lm = lane & 15;
    const int base = blockIdx.x * 64;

    stage_chunk(wp, Ws[0], wave, lane);
    stage_chunk(wp + CHUNK_BYTES, Ws[1], wave, lane);

    // latents (fp32, contiguous) -> Xs bf16 swizzled; fully coalesced loads
    const float4* lat4 = (const float4*)latents;
    const long maxf4 = (long)NSRC * 64 - 1;
    #pragma unroll
    for (int i = 0; i < 16; ++i) {
        int f4 = i * 256 + tid;
        long gidx = (long)base * 64 + f4; if (gidx > maxf4) gidx = maxf4;
        float4 v = lat4[gidx];
        int r = f4 >> 6, g4 = f4 & 63;
        int grp = g4 >> 1, half = g4 & 1;
        union { uint2 u; __hip_bfloat16 h[4]; } pk;
        pk.h[0] = __float2bfloat16(v.x); pk.h[1] = __float2bfloat16(v.y);
        pk.h[2] = __float2bfloat16(v.z); pk.h[3] = __float2bfloat16(v.w);
        *(uint2*)(Xs + r * 512 + ((grp ^ (r & 31)) << 4) + half * 8) = pk.u;
    }
    __syncthreads();

    f32x4 acc[4][4];
    #pragma unroll
    for (int mt = 0; mt < 4; ++mt)
        #pragma unroll
        for (int nt = 0; nt < 4; ++nt) acc[mt][nt] = (f32x4){0.f, 0.f, 0.f, 0.f};

    for (int c = 0; c < 8; ++c) {
        const char* wb = Ws[c & 1];
        bf16x8 a[4], b[4];
        #pragma unroll
        for (int mt = 0; mt < 4; ++mt) {
            int m = wave * 64 + mt * 16 + lm;
            a[mt] = *(const bf16x8*)(wb + m * 64 + ((q ^ ((lm >> 1) & 3)) << 4));
        }
        #pragma unroll
        for (int nt = 0; nt < 4; ++nt) {
            int r = nt * 16 + lm;
            b[nt] = *(const bf16x8*)(Xs + r * 512 + (((c * 4 + q) ^ (r & 31)) << 4));
        }
        #pragma unroll
        for (int mt = 0; mt < 4; ++mt)
            #pragma unroll
            for (int nt = 0; nt < 4; ++nt)
                acc[mt][nt] = __builtin_amdgcn_mfma_f32_16x16x32_bf16(a[mt], b[nt], acc[mt][nt], 0, 0, 0);
        __syncthreads();
        if (c + 2 < 8) stage_chunk(wp + (size_t)(c + 2) * CHUNK_BYTES, Ws[c & 1], wave, lane);
    }

    #pragma unroll
    for (int mt = 0; mt < 4; ++mt) {
        int f0 = wave * 64 + mt * 16 + q * 4;
        float4 bb = *(const float4*)(b_in + f0);
        float bbv[4] = {bb.x, bb.y, bb.z, bb.w};
        #pragma unroll
        for (int nt = 0; nt < 4; ++nt) {
            int srow = base + nt * 16 + lm;
            if (srow < NSRC) {
                union { uint2 u; __hip_bfloat16 h[4]; } pk;
                #pragma unroll
                for (int rg = 0; rg < 4; ++rg)
                    pk.h[rg] = __float2bfloat16(acc[mt][nt][rg] + bbv[rg]);
                *(uint2*)(Yc + (size_t)srow * 512 + f0 * 2) = pk.u;   // no relu here
            }
        }
    }
}

// ---------------- main: per-edge h0=relu(Y[col]+pos@Wpos); L1, L2, fc_out ----------
__global__ __launch_bounds__(256, 2) void interp_main(
    const float* __restrict__ pos_src, const float* __restrict__ pos_tgt,
    const int* __restrict__ rowi, const int* __restrict__ coli,
    const float* __restrict__ Win, const float* __restrict__ b1,
    const char* __restrict__ wp, const char* __restrict__ Yc,
    float* __restrict__ out, int E)
{
    __shared__ __align__(16) char Xs[64 * 512];          // 32768
    __shared__ __align__(16) char Ws[2][CHUNK_BYTES];    // 32768
    __shared__ float wpos[3][256];                       // 3072
    __shared__ float posrel[64][4];                      // 1024
    __shared__ int   cols[64];                           // 256
    __shared__ float red[4][64];                         // 1024

    const int tid = threadIdx.x, wave = tid >> 6, lane = tid & 63;
    const int q = lane >> 4, lm = lane & 15;
    const int base = blockIdx.x * 64;

    // stage L1 chunks 0,1 immediately (slots 8,9 of wpack)
    stage_chunk(wp + (size_t)8 * CHUNK_BYTES, Ws[0], wave, lane);
    stage_chunk(wp + (size_t)9 * CHUNK_BYTES, Ws[1], wave, lane);

    if (tid < 64) {
        int e = base + tid; if (e >= E) e = E - 1;
        int ri = rowi[e], ci = coli[e];
        cols[tid] = ci;
        posrel[tid][0] = pos_tgt[ri * 3 + 0] - pos_src[ci * 3 + 0];
        posrel[tid][1] = pos_tgt[ri * 3 + 1] - pos_src[ci * 3 + 1];
        posrel[tid][2] = pos_tgt[ri * 3 + 2] - pos_src[ci * 3 + 2];
    }
    wpos[0][tid] = Win[(size_t)256 * 256 + tid];
    wpos[1][tid] = Win[(size_t)257 * 256 + tid];
    wpos[2][tid] = Win[(size_t)258 * 256 + tid];
    __syncthreads();                     // cols/posrel/wpos visible

    // gather Y rows straight into LDS (per-lane global addr, zero VALU convert)
    {
        int j = lane & 31, hi = lane >> 5;
        #pragma unroll
        for (int i = 0; i < 8; ++i) {
            int r0 = wave * 16 + i * 2;
            int r  = r0 + hi;
            int cv = cols[r];
            const char* src = Yc + (size_t)cv * 512 + (((j ^ (r & 31)) << 4) - (size_t)lane * 16);
            __builtin_amdgcn_global_load_lds(AS1U32(src + lane * 16),
                                             AS3U32(Xs + r0 * 512), 16, 0, 0);
        }
    }
    __syncthreads();                     // gather complete

    // pos-pass: Xs = relu(Xs + posrel @ Wpos), in place, fp32 math
    {
        int r = tid >> 2, qt = tid & 3;
        float p0 = posrel[r][0], p1 = posrel[r][1], p2 = posrel[r][2];
        #pragma unroll
        for (int i = 0; i < 8; ++i) {
            int s = qt * 8 + ((i + r) & 7);
            int g = s ^ (r & 31);
            int f = g * 8;
            char* addr = Xs + r * 512 + (s << 4);
            union { bf16x8 v; __hip_bfloat16 h[8]; } u;
            u.v = *(bf16x8*)addr;
            float4 wa0 = *(const float4*)&wpos[0][f], wa1 = *(const float4*)&wpos[0][f + 4];
            float4 wb0 = *(const float4*)&wpos[1][f], wb1 = *(const float4*)&wpos[1][f + 4];
            float4 wc0 = *(const float4*)&wpos[2][f], wc1 = *(const float4*)&wpos[2][f + 4];
            float av[8] = {wa0.x, wa0.y, wa0.z, wa0.w, wa1.x, wa1.y, wa1.z, wa1.w};
            float bv[8] = {wb0.x, wb0.y, wb0.z, wb0.w, wb1.x, wb1.y, wb1.z, wb1.w};
            float cv[8] = {wc0.x, wc0.y, wc0.z, wc0.w, wc1.x, wc1.y, wc1.z, wc1.w};
            #pragma unroll
            for (int k = 0; k < 8; ++k) {
                float v = __bfloat162float(u.h[k]) + p0 * av[k] + p1 * bv[k] + p2 * cv[k];
                if (v < 0.f) v = 0.f;
                u.h[k] = __float2bfloat16(v);
            }
            *(bf16x8*)addr = u.v;
        }
    }
    __syncthreads();                     // Xs = L1 input

    f32x4 acc[4][4];
    #pragma unroll
    for (int mt = 0; mt < 4; ++mt)
        #pragma unroll
        for (int nt = 0; nt < 4; ++nt) acc[mt][nt] = (f32x4){0.f, 0.f, 0.f, 0.f};

    for (int cc = 0; cc < 16; ++cc) {    // cc 0..7 = L1 (slots 8..15), 8..15 = L2 (16..23)
        const int c = cc & 7;
        const char* wb = Ws[cc & 1];
        bf16x8 a[4], b[4];
        #pragma unroll
        for (int mt = 0; mt < 4; ++mt) {
            int m = wave * 64 + mt * 16 + lm;
            a[mt] = *(const bf16x8*)(wb + m * 64 + ((q ^ ((lm >> 1) & 3)) << 4));
        }
        #pragma unroll
        for (int nt = 0; nt < 4; ++nt) {
            int r = nt * 16 + lm;
            b[nt] = *(const bf16x8*)(Xs + r * 512 + (((c * 4 + q) ^ (r & 31)) << 4));
        }
        #pragma unroll
        for (int mt = 0; mt < 4; ++mt)
            #pragma unroll
            for (int nt = 0; nt < 4; ++nt)
                acc[mt][nt] = __builtin_amdgcn_mfma_f32_16x16x32_bf16(a[mt], b[nt], acc[mt][nt], 0, 0, 0);
        __syncthreads();                 // all waves done with Ws[cc&1] (and Xs if cc==7)

        if (cc + 2 < 16)
            stage_chunk(wp + (size_t)(8 + cc + 2) * CHUNK_BYTES, Ws[cc & 1], wave, lane);

        if (cc == 7) {                   // L1 epilogue: Xs = relu(acc + b1), b64 writes
            #pragma unroll
            for (int mt = 0; mt < 4; ++mt) {
                int f0 = wave * 64 + mt * 16 + q * 4;
                float4 bb = *(const float4*)(b1 + f0);
                float bbv[4] = {bb.x, bb.y, bb.z, bb.w};
                int gf = f0 >> 3;
                #pragma unroll
                for (int nt = 0; nt < 4; ++nt) {
                    int r = nt * 16 + lm;
                    union { uint2 u; __hip_bfloat16 h[4]; } pk;
                    #pragma unroll
                    for (int rg = 0; rg < 4; ++rg) {
                        float v = acc[mt][nt][rg] + bbv[rg];
                        if (v < 0.f) v = 0.f;
                        pk.h[rg] = __float2bfloat16(v);
                        acc[mt][nt][rg] = 0.f;
                    }
                    *(uint2*)(Xs + r * 512 + ((gf ^ (r & 31)) << 4) + (q & 1) * 8) = pk.u;
                }
            }
            __syncthreads();             // Xs = L2 input (also drains chunk-9... chunk staging)
        }
    }

    // final: out[e] = sum_f acc[f][e]*w0[f] + S   (b2,b_out folded into S)
    const float4* w0f4 = (const float4*)(wp + W0_OFF);
    const float S = *(const float*)(wp + S_OFF);
    float partial[4] = {0.f, 0.f, 0.f, 0.f};
    #pragma unroll
    for (int mt = 0; mt < 4; ++mt) {
        float4 w4 = w0f4[wave * 16 + mt * 4 + q];
        float wv[4] = {w4.x, w4.y, w4.z, w4.w};
        #pragma unroll
        for (int nt = 0; nt < 4; ++nt)
            #pragma unroll
            for (int rg = 0; rg < 4; ++rg)
                partial[nt] += acc[mt][nt][rg] * wv[rg];
    }
    #pragma unroll
    for (int nt = 0; nt < 4; ++nt) {
        float v = partial[nt];
        v += __shfl_xor(v, 16);
        v += __shfl_xor(v, 32);          // summed over q (features within wave)
        if (lane < 16) red[wave][nt * 16 + lane] = v;
    }
    __syncthreads();
    if (tid < 64) {
        int e = base + tid;
        if (e < E) out[e] = red[0][tid] + red[1][tid] + red[2][tid] + red[3][tid] + S;
    }
}

extern "C" void kernel_launch(void* const* d_in, const int* in_sizes, int n_in,
                              void* d_out, int out_size, void* d_ws, size_t ws_size,
                              hipStream_t stream)
{
    const float* pos_src = (const float*)d_in[0];
    const float* pos_tgt = (const float*)d_in[1];
    const float* latents = (const float*)d_in[2];
    const int*   rowi    = (const int*)d_in[3];
    const int*   coli    = (const int*)d_in[4];
    const float* Win     = (const float*)d_in[5];
    const float* b_in    = (const float*)d_in[6];
    const float* W1      = (const float*)d_in[7];
    const float* b1      = (const float*)d_in[8];
    const float* W2      = (const float*)d_in[9];
    const float* b2      = (const float*)d_in[10];
    const float* Wout    = (const float*)d_in[11];
    const float* b_out   = (const float*)d_in[12];
    float* out = (float*)d_out;
    const int E = in_sizes[3];

    char* wp = (char*)d_ws;             // 24 chunks + w0 + S; Y at Y_OFF (needs ~52 MB)
    char* Yc = wp + Y_OFF;

    pack_weights<<<25, 256, 0, stream>>>(Win, W1, W2, Wout, b2, b_out, wp);
    precompute_y<<<(NSRC + 63) / 64, 256, 0, stream>>>(latents, b_in, wp, Yc);
    interp_main<<<(E + 63) / 64, 256, 0, stream>>>(pos_src, pos_tgt, rowi, coli,
                                                   Win, b1, wp, Yc, out, E);
}

// Round 3
// 311.240 us; speedup vs baseline: 2.3379x; 1.3386x over previous
//
#include <hip/hip_runtime.h>
#include <hip/hip_bf16.h>
#include <stdint.h>

typedef __attribute__((ext_vector_type(8))) short bf16x8;
typedef __attribute__((ext_vector_type(4))) float f32x4;

#define NSRC 100000
#define WIN_OFF 0                    // Win[0:256] A-frag pack, 128 KB
#define W1P_OFF (128*1024)           // W1 A-frag pack, 128 KB
#define BU_OFF  (256*1024)           // float2 bu[256] = (b1[f], u[f])
#define SS_OFF  (BU_OFF + 2048)      // float S = b2.w0 + b_out0
#define Y_OFF   (264*1024)           // bf16 Y[NSRC][256] (512 B rows)

#define PAIRB 1040                   // 2 rows (1024 B) + 16 B pad -> 2-way max bank alias
#define XBYTES (32*PAIRB)            // 33280 B per buffer (64 rows)
#define POFF(r) (((r)>>1)*PAIRB + ((r)&1)*512)

#define AS3U32(p) ((__attribute__((address_space(3))) uint32_t*)(uintptr_t)(p))
#define AS1U32(p) ((const __attribute__((address_space(1))) uint32_t*)(uintptr_t)(p))

// A-frag-direct pack: frag for (k-chunk c, feature m, quad q) holds W[k=c*32+q*8+j][m]
// at byte offset c*16384 + m*64 + q*16.
__global__ __launch_bounds__(256) void pack_kernel(
    const float* __restrict__ Win, const float* __restrict__ W1,
    const float* __restrict__ W2, const float* __restrict__ Wout,
    const float* __restrict__ b1, const float* __restrict__ b2,
    const float* __restrict__ b_out, char* __restrict__ wp)
{
    const int t = threadIdx.x, blk = blockIdx.x;
    if (blk < 16) {                            // A-frag packs (coalesced row reads)
        const float* W = (blk < 8) ? Win : W1;
        char* dst = wp + ((blk < 8) ? WIN_OFF : W1P_OFF);
        const int c = blk & 7;
        #pragma unroll
        for (int q = 0; q < 4; ++q) {
            union { bf16x8 v; __hip_bfloat16 h[8]; } u;
            #pragma unroll
            for (int j = 0; j < 8; ++j)
                u.h[j] = __float2bfloat16(W[(size_t)(c*32 + q*8 + j)*256 + t]);
            *(bf16x8*)(dst + c*16384 + t*64 + q*16) = u.v;
        }
    } else if (blk < 24) {                     // u[f] = sum_n W2[f][n]*w0[n]; bu=(b1,u)
        __shared__ float w0s[256];
        w0s[t] = Wout[t*2];
        __syncthreads();
        const int b = blk - 16, fl = t >> 3, sub = t & 7, f = b*32 + fl;
        const float* row = W2 + (size_t)f*256 + sub*32;
        float p = 0.f;
        #pragma unroll
        for (int j = 0; j < 32; ++j) p += row[j]*w0s[sub*32 + j];
        p += __shfl_xor(p,1); p += __shfl_xor(p,2); p += __shfl_xor(p,4);
        if (sub == 0) {
            float2 v; v.x = b1[f]; v.y = p;
            *(float2*)(wp + BU_OFF + f*8) = v;
        }
    } else {                                   // S = dot(b2,w0) + b_out0
        __shared__ float rb[4];
        float v = b2[t]*Wout[t*2];
        v += __shfl_xor(v,1); v += __shfl_xor(v,2); v += __shfl_xor(v,4);
        v += __shfl_xor(v,8); v += __shfl_xor(v,16); v += __shfl_xor(v,32);
        if ((t&63) == 0) rb[t>>6] = v;
        __syncthreads();
        if (t == 0) *(float*)(wp + SS_OFF) = rb[0]+rb[1]+rb[2]+rb[3] + b_out[0];
    }
}

// Y[s] = latents[s] @ Win[0:256] + b_in   (bf16, no relu — pos added per-edge later)
__global__ __launch_bounds__(256, 2) void precompute_y(
    const float* __restrict__ latents, const float* __restrict__ b_in,
    const char* __restrict__ wp, char* __restrict__ Yc)
{
    __shared__ __align__(16) char Xs[XBYTES];
    __shared__ float binS[256];
    const int tid = threadIdx.x, wave = tid >> 6, lane = tid & 63;
    const int q = lane >> 4, lm = lane & 15;

    bf16x8 wA[4][8];                           // Win slice: 64 feats/wave, 128 VGPR
    {
        const char* wb = wp + WIN_OFF;
        #pragma unroll
        for (int mt = 0; mt < 4; ++mt) {
            const int m = wave*64 + mt*16 + lm;
            #pragma unroll
            for (int c = 0; c < 8; ++c)
                wA[mt][c] = *(const bf16x8*)(wb + c*16384 + m*64 + q*16);
        }
    }
    binS[tid] = b_in[tid];

    const int ntY = (NSRC + 63) / 64;
    for (int tile = blockIdx.x; tile < ntY; tile += 512) {
        const int base = tile*64;
        {                                      // fp32 latents -> bf16 LDS, coalesced
            const int r = tid & 63, h = tid >> 6;
            int srow = base + r; if (srow >= NSRC) srow = NSRC - 1;
            const float4* lp = (const float4*)(latents + (size_t)srow*256 + h*64);
            #pragma unroll
            for (int w = 0; w < 8; ++w) {
                float4 v0 = lp[w*2], v1 = lp[w*2+1];
                union { bf16x8 v; __hip_bfloat16 hh[8]; } u;
                u.hh[0]=__float2bfloat16(v0.x); u.hh[1]=__float2bfloat16(v0.y);
                u.hh[2]=__float2bfloat16(v0.z); u.hh[3]=__float2bfloat16(v0.w);
                u.hh[4]=__float2bfloat16(v1.x); u.hh[5]=__float2bfloat16(v1.y);
                u.hh[6]=__float2bfloat16(v1.z); u.hh[7]=__float2bfloat16(v1.w);
                *(bf16x8*)(Xs + POFF(r) + h*128 + w*16) = u.v;
            }
        }
        __syncthreads();
        f32x4 acc[4][4];
        #pragma unroll
        for (int mt = 0; mt < 4; ++mt)
            #pragma unroll
            for (int nt = 0; nt < 4; ++nt) acc[mt][nt] = (f32x4){0.f,0.f,0.f,0.f};
        #pragma unroll
        for (int c = 0; c < 8; ++c) {
            bf16x8 b[4];
            #pragma unroll
            for (int nt = 0; nt < 4; ++nt)
                b[nt] = *(const bf16x8*)(Xs + POFF(nt*16+lm) + c*64 + q*16);
            #pragma unroll
            for (int mt = 0; mt < 4; ++mt)
                #pragma unroll
                for (int nt = 0; nt < 4; ++nt)
                    acc[mt][nt] = __builtin_amdgcn_mfma_f32_16x16x32_bf16(wA[mt][c], b[nt], acc[mt][nt], 0,0,0);
        }
        #pragma unroll
        for (int mt = 0; mt < 4; ++mt) {
            const int f0 = wave*64 + mt*16 + q*4;
            float4 bb = *(const float4*)&binS[f0];
            float bbv[4] = {bb.x, bb.y, bb.z, bb.w};
            #pragma unroll
            for (int nt = 0; nt < 4; ++nt) {
                const int srow = base + nt*16 + lm;
                if (srow < NSRC) {
                    union { uint2 uu; __hip_bfloat16 hh[4]; } pk;
                    #pragma unroll
                    for (int rg = 0; rg < 4; ++rg)
                        pk.hh[rg] = __float2bfloat16(acc[mt][nt][rg] + bbv[rg]);
                    *(uint2*)(Yc + (size_t)srow*512 + f0*2) = pk.uu;
                }
            }
        }
        __syncthreads();
    }
}

// out[e] = relu( relu(Y[col]+pos@Wpos) @ W1 + b1 ) . u + S
__global__ __launch_bounds__(256, 2) void interp_main(
    const float* __restrict__ pos_src, const float* __restrict__ pos_tgt,
    const int* __restrict__ rowi, const int* __restrict__ coli,
    const float* __restrict__ Win, const char* __restrict__ wp,
    const char* __restrict__ Yc, float* __restrict__ out,
    int E, int ntiles)
{
    __shared__ __align__(16) char Xs[2][XBYTES];   // 66560
    __shared__ float wposI[32][24];                // interleaved: [fseg][dim*8+j]
    __shared__ float buS[512];                     // float2[256] = (b1,u)
    __shared__ float posrel[2][64][4];
    __shared__ int   colsS[2][64];
    __shared__ float red[4][64];

    const int tid = threadIdx.x, wave = tid >> 6, lane = tid & 63;
    const int q = lane >> 4, lm = lane & 15;
    const int bid = blockIdx.x;

    bf16x8 wA[4][8];                               // W1 slice, 128 VGPR, loaded once
    {
        const char* wb = wp + W1P_OFF;
        #pragma unroll
        for (int mt = 0; mt < 4; ++mt) {
            const int m = wave*64 + mt*16 + lm;
            #pragma unroll
            for (int c = 0; c < 8; ++c)
                wA[mt][c] = *(const bf16x8*)(wb + c*16384 + m*64 + q*16);
        }
    }
    {
        #pragma unroll
        for (int s = 0; s < 3; ++s)
            wposI[tid >> 3][s*8 + (tid & 7)] = Win[(size_t)(256+s)*256 + tid];
        *(float2*)&buS[tid*2] = *(const float2*)(wp + BU_OFF + tid*8);
    }
    const float Sv = *(const float*)(wp + SS_OFF);
    const int niter = (ntiles - bid + 511) / 512;

    // prologue: meta for iterations 0,1
    #pragma unroll
    for (int ii = 0; ii < 2; ++ii) {
        if (tid < 64) {
            long tt = (long)bid + (long)ii*512; if (tt >= ntiles) tt = ntiles - 1;
            long e = tt*64 + tid; if (e >= E) e = E - 1;
            int ri = rowi[e], ci = coli[e];
            colsS[ii][tid] = ci;
            float4 pr;
            pr.x = pos_tgt[ri*3+0] - pos_src[ci*3+0];
            pr.y = pos_tgt[ri*3+1] - pos_src[ci*3+1];
            pr.z = pos_tgt[ri*3+2] - pos_src[ci*3+2];
            pr.w = 0.f;
            *(float4*)&posrel[ii][tid][0] = pr;
        }
    }
    __syncthreads();
    {                                              // gather tile 0 -> Xs[0]
        #pragma unroll
        for (int k2 = 0; k2 < 8; ++k2) {
            const int r0 = wave*16 + k2*2;
            const int row = r0 + (lane >> 5);
            const int cv = colsS[0][row];
            const char* src = Yc + (size_t)cv*512 + (lane & 31)*16;
            __builtin_amdgcn_global_load_lds(AS1U32(src), AS3U32(Xs[0] + (r0>>1)*PAIRB), 16, 0, 0);
        }
    }

    for (int i = 0; i < niter; ++i) {
        const int p = i & 1;
        __syncthreads();                           // A: gather(i) drained, Xs[p] ready

        // ---- phase1 ----
        if (i > 0 && tid < 64) {                   // out-store for tile i-1
            long e = ((long)bid + (long)(i-1)*512)*64 + tid;
            if (e < E) out[e] = red[0][tid]+red[1][tid]+red[2][tid]+red[3][tid] + Sv;
        }
        int m_ci = 0; float4 m_pr = {0.f,0.f,0.f,0.f};   // meta loads for i+2
        if (tid < 64) {
            long tt = (long)bid + (long)(i+2)*512; if (tt >= ntiles) tt = ntiles - 1;
            long e = tt*64 + tid; if (e >= E) e = E - 1;
            int ri = rowi[e]; m_ci = coli[e];
            m_pr.x = pos_tgt[ri*3+0] - pos_src[m_ci*3+0];
            m_pr.y = pos_tgt[ri*3+1] - pos_src[m_ci*3+1];
            m_pr.z = pos_tgt[ri*3+2] - pos_src[m_ci*3+2];
        }
        {                                          // pos-pass: Xs[p] = relu(Y + pos@Wpos)
            const int fs = tid & 31, rb = tid >> 5;
            float w0v[8], w1v[8], w2v[8];
            {
                const float* wi = &wposI[fs][0];
                #pragma unroll
                for (int j = 0; j < 8; ++j) { w0v[j]=wi[j]; w1v[j]=wi[8+j]; w2v[j]=wi[16+j]; }
            }
            char* xb = Xs[p];
            #pragma unroll
            for (int ii2 = 0; ii2 < 8; ++ii2) {
                const int r = rb*8 + ii2;
                float4 pr = *(const float4*)&posrel[p][r][0];
                char* addr = xb + POFF(r) + fs*16;
                union { bf16x8 v; __hip_bfloat16 h[8]; } u;
                u.v = *(bf16x8*)addr;
                #pragma unroll
                for (int j = 0; j < 8; ++j) {
                    float vv = __bfloat162float(u.h[j]) + pr.x*w0v[j] + pr.y*w1v[j] + pr.z*w2v[j];
                    u.h[j] = __float2bfloat16(vv < 0.f ? 0.f : vv);
                }
                *(bf16x8*)addr = u.v;
            }
        }
        __syncthreads();                           // B

        // ---- phase2 ----
        {                                          // gather(i+1) -> Xs[1-p]; in flight across MFMA
            const int s = 1 - p;
            char* xb = Xs[s];
            #pragma unroll
            for (int k2 = 0; k2 < 8; ++k2) {
                const int r0 = wave*16 + k2*2;
                const int row = r0 + (lane >> 5);
                const int cv = colsS[s][row];
                const char* src = Yc + (size_t)cv*512 + (lane & 31)*16;
                __builtin_amdgcn_global_load_lds(AS1U32(src), AS3U32(xb + (r0>>1)*PAIRB), 16, 0, 0);
            }
        }
        f32x4 acc[4][4];
        #pragma unroll
        for (int mt = 0; mt < 4; ++mt)
            #pragma unroll
            for (int nt = 0; nt < 4; ++nt) acc[mt][nt] = (f32x4){0.f,0.f,0.f,0.f};
        {
            const char* xb = Xs[p];
            #pragma unroll
            for (int c = 0; c < 8; ++c) {
                bf16x8 b[4];
                #pragma unroll
                for (int nt = 0; nt < 4; ++nt)
                    b[nt] = *(const bf16x8*)(xb + POFF(nt*16+lm) + c*64 + q*16);
                #pragma unroll
                for (int mt = 0; mt < 4; ++mt)
                    #pragma unroll
                    for (int nt = 0; nt < 4; ++nt)
                        acc[mt][nt] = __builtin_amdgcn_mfma_f32_16x16x32_bf16(wA[mt][c], b[nt], acc[mt][nt], 0,0,0);
            }
        }
        float partial[4] = {0.f,0.f,0.f,0.f};      // epilogue: relu(h1+b1).u, all fp32
        #pragma unroll
        for (int mt = 0; mt < 4; ++mt) {
            const int f0 = wave*64 + mt*16 + q*4;
            float4 bu0 = *(const float4*)&buS[f0*2];
            float4 bu1 = *(const float4*)&buS[f0*2 + 4];
            float b1v[4] = {bu0.x, bu0.z, bu1.x, bu1.z};
            float uv[4]  = {bu0.y, bu0.w, bu1.y, bu1.w};
            #pragma unroll
            for (int nt = 0; nt < 4; ++nt)
                #pragma unroll
                for (int rg = 0; rg < 4; ++rg) {
                    float h = acc[mt][nt][rg] + b1v[rg];
                    if (h > 0.f) partial[nt] += h * uv[rg];
                }
        }
        #pragma unroll
        for (int nt = 0; nt < 4; ++nt) {
            float v = partial[nt];
            v += __shfl_xor(v, 16);
            v += __shfl_xor(v, 32);
            if (lane < 16) red[wave][nt*16 + lane] = v;
        }
        if (tid < 64) {                            // meta writes for i+2 (slot p)
            colsS[p][tid] = m_ci;
            *(float4*)&posrel[p][tid][0] = m_pr;
        }
    }
    __syncthreads();
    if (tid < 64) {                                // final tile's out-store
        long e = ((long)bid + (long)(niter-1)*512)*64 + tid;
        if (e < E) out[e] = red[0][tid]+red[1][tid]+red[2][tid]+red[3][tid] + Sv;
    }
}

extern "C" void kernel_launch(void* const* d_in, const int* in_sizes, int n_in,
                              void* d_out, int out_size, void* d_ws, size_t ws_size,
                              hipStream_t stream)
{
    const float* pos_src = (const float*)d_in[0];
    const float* pos_tgt = (const float*)d_in[1];
    const float* latents = (const float*)d_in[2];
    const int*   rowi    = (const int*)d_in[3];
    const int*   coli    = (const int*)d_in[4];
    const float* Win     = (const float*)d_in[5];
    const float* b_in    = (const float*)d_in[6];
    const float* W1      = (const float*)d_in[7];
    const float* b1      = (const float*)d_in[8];
    const float* W2      = (const float*)d_in[9];
    const float* b2      = (const float*)d_in[10];
    const float* Wout    = (const float*)d_in[11];
    const float* b_out   = (const float*)d_in[12];
    float* out = (float*)d_out;
    const int E = in_sizes[3];
    const int ntiles = (E + 63) / 64;

    char* wp = (char*)d_ws;                  // packs ~264 KB + Y 51.2 MB
    char* Yc = wp + Y_OFF;

    pack_kernel<<<25, 256, 0, stream>>>(Win, W1, W2, Wout, b1, b2, b_out, wp);
    precompute_y<<<512, 256, 0, stream>>>(latents, b_in, wp, Yc);
    interp_main<<<512, 256, 0, stream>>>(pos_src, pos_tgt, rowi, coli,
                                         Win, wp, Yc, out, E, ntiles);
}